// Round 1
// baseline (309.381 us; speedup 1.0000x reference)
//
#include <hip/hip_runtime.h>
#include <stdint.h>

#define NROWS 4
#define WCOLS 368
#define KREG  6          // ceil(368/64)
#define KS_FLOATS 30146560   // 4*16*640*368*2
#define KS_F4     7536640    // /4
#define PER_B_F4  1884160    // 16*640*368*2/4
#define ROW_F4    184        // 368*2/4

// ---------------- Threefry-2x32, 20 rounds (JAX-compatible) ----------------
__device__ __forceinline__ void tf_block(uint32_t k0, uint32_t k1,
                                         uint32_t x0, uint32_t x1,
                                         uint32_t& o0, uint32_t& o1) {
  const uint32_t ks2 = k0 ^ k1 ^ 0x1BD11BDAu;
#define TFR(r) { x0 += x1; x1 = (x1 << (r)) | (x1 >> (32 - (r))); x1 ^= x0; }
  x0 += k0; x1 += k1;
  TFR(13) TFR(15) TFR(26) TFR(6)
  x0 += k1;  x1 += ks2 + 1u;
  TFR(17) TFR(29) TFR(16) TFR(24)
  x0 += ks2; x1 += k0 + 2u;
  TFR(13) TFR(15) TFR(26) TFR(6)
  x0 += k0;  x1 += k1 + 3u;
  TFR(17) TFR(29) TFR(16) TFR(24)
  x0 += k1;  x1 += ks2 + 4u;
  TFR(13) TFR(15) TFR(26) TFR(6)
  x0 += ks2; x1 += k0 + 5u;
#undef TFR
  o0 = x0; o1 = x1;
}

__device__ __forceinline__ float wave_sum_f(float v) {
  #pragma unroll
  for (int off = 32; off >= 1; off >>= 1) v += __shfl_xor(v, off, 64);
  return v;
}
__device__ __forceinline__ float wave_max_f(float v) {
  #pragma unroll
  for (int off = 32; off >= 1; off >>= 1) v = fmaxf(v, __shfl_xor(v, off, 64));
  return v;
}
__device__ __forceinline__ int wave_sum_i(int v) {
  #pragma unroll
  for (int off = 32; off >= 1; off >>= 1) v += __shfl_xor(v, off, 64);
  return v;
}

// One wave per batch row: prob pipeline + JAX-exact rejection sampling.
__global__ __launch_bounds__(64) void sample_rows(const float* __restrict__ mask,
                                                  const float* __restrict__ sampler,
                                                  float* __restrict__ new_mask,
                                                  float* __restrict__ fpm) {
  const int b = blockIdx.x;
  const int l = threadIdx.x;

  float mk[KREG], pmv[KREG], mp[KREG], m0[KREG], x[KREG];

  // softplus(10*s)/10 (JAX: max(z,0)+log1p(exp(-|z|)))
  float vmax = 0.0f;
  #pragma unroll
  for (int k = 0; k < KREG; ++k) {
    const int w = l + 64 * k;
    if (w < WCOLS) {
      const float s  = sampler[w];
      const float mv = mask[b * WCOLS + w];
      const float z  = 10.0f * s;
      const float sp = (fmaxf(z, 0.0f) + log1pf(expf(-fabsf(z)))) / 10.0f;
      mk[k] = mv; pmv[k] = sp;
      vmax = fmaxf(vmax, (1.0f - mv) * sp);
    } else { mk[k] = 1.0f; pmv[k] = 0.0f; }
  }
  const float denom = wave_max_f(vmax);

  // normalize, mask, per-row stats
  float cnt0 = 0.0f, smp = 0.0f;
  #pragma unroll
  for (int k = 0; k < KREG; ++k) {
    const int w = l + 64 * k;
    if (w < WCOLS) {
      const float pn  = pmv[k] / denom;
      const float mpv = pn * (1.0f - mk[k]);
      const float z0  = (mk[k] == 0.0f) ? 1.0f : 0.0f;
      mp[k] = mpv; m0[k] = z0;
      cnt0 += z0; smp += mpv * z0;
    } else { mp[k] = 0.0f; m0[k] = 0.0f; }
  }
  const float count    = wave_sum_f(cnt0);
  const float sumx     = wave_sum_f(smp);
  const float sparsity = 92.0f / count;
  const float xbar_pre = sumx / count;
  const float r    = sparsity / xbar_pre;
  const float beta = (1.0f - sparsity) / (1.0f - xbar_pre);
  const bool  le   = (r <= 1.0f);

  float sx = 0.0f;
  #pragma unroll
  for (int k = 0; k < KREG; ++k) {
    const int w = l + 64 * k;
    if (w < WCOLS) {
      const float resc = le ? (mp[k] * r) : (1.0f - (1.0f - mp[k]) * beta);
      const float xv   = (m0[k] > 0.0f) ? resc : mp[k];
      x[k] = xv; sx += xv;
    } else x[k] = 0.0f;
  }
  const float xbar = wave_sum_f(sx) / 368.0f;

  // row key: partitionable split -> block (0, b) of key (0, 42)
  uint32_t key0, key1;
  tf_block(0u, 42u, 0u, (uint32_t)b, key0, key1);

  // rejection loop: do { split; draw; count } while(!ok && cnt<2000)
  int cnt = 0;
  bool ok = false;
  uint32_t res = 0;
  do {
    uint32_t nk0, nk1, sb0, sb1;
    tf_block(key0, key1, 0u, 0u, nk0, nk1);   // new key = keys_out[0]
    tf_block(key0, key1, 0u, 1u, sb0, sb1);   // sub     = keys_out[1]
    key0 = nk0; key1 = nk1;

    res = 0;
    int myones = 0;
    #pragma unroll
    for (int k = 0; k < KREG; ++k) {
      const int w = l + 64 * k;
      if (w < WCOLS) {
        uint32_t y0, y1;
        tf_block(sb0, sb1, 0u, (uint32_t)w, y0, y1);
        const uint32_t bits = y0 ^ y1;                       // partitionable fold
        const float prob = fmaxf(0.0f,
            __uint_as_float((bits >> 9) | 0x3f800000u) - 1.0f);
        if (x[k] > prob) { res |= (1u << k); ++myones; }
      }
    }
    const int tot = wave_sum_i(myones);
    ++cnt;
    const float meanr = (float)tot / 368.0f;
    ok = fabsf(meanr - xbar) <= (1e-3f + 1e-5f * fabsf(xbar));
  } while (!ok && cnt < 2000);

  #pragma unroll
  for (int k = 0; k < KREG; ++k) {
    const int w = l + 64 * k;
    if (w < WCOLS) {
      const float acq = ((res >> k) & 1u) ? 1.0f : 0.0f;
      new_mask[b * WCOLS + w] = mk[k] + acq;
      fpm[b * WCOLS + w]      = x[k];
    }
  }
}

// Elementwise masked kspace. Sign-fix in ref == "+0 wherever mask==0".
__global__ __launch_bounds__(256) void apply_mask(const float4* __restrict__ ks,
                                                  const float* __restrict__ nm,
                                                  float4* __restrict__ out) {
  const int q = blockIdx.x * 256 + threadIdx.x;   // grid covers KS_F4 exactly
  const int b  = q / PER_B_F4;
  const int qw = q % ROW_F4;
  const int w0 = qw * 2;
  const float mA = nm[b * WCOLS + w0];
  const float mB = nm[b * WCOLS + w0 + 1];
  const float4 v = ks[q];
  float4 o;
  o.x = (mA != 0.0f) ? mA * v.x : 0.0f;
  o.y = (mA != 0.0f) ? mA * v.y : 0.0f;
  o.z = (mB != 0.0f) ? mB * v.z : 0.0f;
  o.w = (mB != 0.0f) ? mB * v.w : 0.0f;
  out[q] = o;
}

extern "C" void kernel_launch(void* const* d_in, const int* in_sizes, int n_in,
                              void* d_out, int out_size, void* d_ws, size_t ws_size,
                              hipStream_t stream) {
  const float* mask    = (const float*)d_in[0];
  const float* kspace  = (const float*)d_in[1];
  const float* sampler = (const float*)d_in[2];

  float* out      = (float*)d_out;
  float* new_mask = out;                              // B*W = 1472
  float* mkspace  = out + NROWS * WCOLS;              // 30146560
  float* fpm      = out + NROWS * WCOLS + KS_FLOATS;  // 1472

  sample_rows<<<NROWS, 64, 0, stream>>>(mask, sampler, new_mask, fpm);
  apply_mask<<<KS_F4 / 256, 256, 0, stream>>>((const float4*)kspace, new_mask,
                                              (float4*)mkspace);
}

// Round 2
// 267.824 us; speedup vs baseline: 1.1552x; 1.1552x over previous
//
#include <hip/hip_runtime.h>
#include <stdint.h>

#define NROWS 4
#define WCOLS 368
#define KREG  6          // ceil(368/64)
#define NWAVE 16         // tries evaluated per super-iteration
#define KS_FLOATS 30146560   // 4*16*640*368*2
#define KS_F4     7536640    // /4
#define PER_B_F4  1884160    // 16*640*368*2/4
#define ROW_F4    184        // 368*2/4

// ---------------- Threefry-2x32, 20 rounds (JAX-compatible) ----------------
__device__ __forceinline__ void tf_block(uint32_t k0, uint32_t k1,
                                         uint32_t x0, uint32_t x1,
                                         uint32_t& o0, uint32_t& o1) {
  const uint32_t ks2 = k0 ^ k1 ^ 0x1BD11BDAu;
#define TFR(r) { x0 += x1; x1 = (x1 << (r)) | (x1 >> (32 - (r))); x1 ^= x0; }
  x0 += k0; x1 += k1;
  TFR(13) TFR(15) TFR(26) TFR(6)
  x0 += k1;  x1 += ks2 + 1u;
  TFR(17) TFR(29) TFR(16) TFR(24)
  x0 += ks2; x1 += k0 + 2u;
  TFR(13) TFR(15) TFR(26) TFR(6)
  x0 += k0;  x1 += k1 + 3u;
  TFR(17) TFR(29) TFR(16) TFR(24)
  x0 += k1;  x1 += ks2 + 4u;
  TFR(13) TFR(15) TFR(26) TFR(6)
  x0 += ks2; x1 += k0 + 5u;
#undef TFR
  o0 = x0; o1 = x1;
}

__device__ __forceinline__ float wave_sum_f(float v) {
  #pragma unroll
  for (int off = 32; off >= 1; off >>= 1) v += __shfl_xor(v, off, 64);
  return v;
}
__device__ __forceinline__ float wave_max_f(float v) {
  #pragma unroll
  for (int off = 32; off >= 1; off >>= 1) v = fmaxf(v, __shfl_xor(v, off, 64));
  return v;
}
__device__ __forceinline__ int wave_sum_i(int v) {
  #pragma unroll
  for (int off = 32; off >= 1; off >>= 1) v += __shfl_xor(v, off, 64);
  return v;
}

// One 1024-thread block per batch row. 16 waves evaluate 16 consecutive
// tries concurrently (self-advancing Threefry key ladder); LDS accept-flag
// scan preserves the sequential first-accept semantics of the reference's
// rejection loop.
__global__ __launch_bounds__(1024) void sample_rows(const float* __restrict__ mask,
                                                    const float* __restrict__ sampler,
                                                    float* __restrict__ new_mask,
                                                    float* __restrict__ fpm) {
  const int b = blockIdx.x;
  const int w = threadIdx.x >> 6;   // wave id 0..15 == try offset within group
  const int l = threadIdx.x & 63;

  __shared__ int acc_ls[NWAVE];

  // ---- Phase 1: probability pipeline (redundant per wave; identical fp ops
  // across waves -> identical x[], xbar in every wave) ----
  float mk[KREG], pmv[KREG], mp[KREG], m0[KREG], x[KREG];

  float vmax = 0.0f;
  #pragma unroll
  for (int k = 0; k < KREG; ++k) {
    const int c = l + 64 * k;
    if (c < WCOLS) {
      const float s  = sampler[c];
      const float mv = mask[b * WCOLS + c];
      const float z  = 10.0f * s;
      const float sp = (fmaxf(z, 0.0f) + log1pf(expf(-fabsf(z)))) / 10.0f;
      mk[k] = mv; pmv[k] = sp;
      vmax = fmaxf(vmax, (1.0f - mv) * sp);
    } else { mk[k] = 1.0f; pmv[k] = 0.0f; }
  }
  const float denom = wave_max_f(vmax);

  float cnt0 = 0.0f, smp = 0.0f;
  #pragma unroll
  for (int k = 0; k < KREG; ++k) {
    const int c = l + 64 * k;
    if (c < WCOLS) {
      const float pn  = pmv[k] / denom;
      const float mpv = pn * (1.0f - mk[k]);
      const float z0  = (mk[k] == 0.0f) ? 1.0f : 0.0f;
      mp[k] = mpv; m0[k] = z0;
      cnt0 += z0; smp += mpv * z0;
    } else { mp[k] = 0.0f; m0[k] = 0.0f; }
  }
  const float count    = wave_sum_f(cnt0);
  const float sumx     = wave_sum_f(smp);
  const float sparsity = 92.0f / count;
  const float xbar_pre = sumx / count;
  const float r    = sparsity / xbar_pre;
  const float beta = (1.0f - sparsity) / (1.0f - xbar_pre);
  const bool  le   = (r <= 1.0f);

  float sx = 0.0f;
  #pragma unroll
  for (int k = 0; k < KREG; ++k) {
    const int c = l + 64 * k;
    if (c < WCOLS) {
      const float resc = le ? (mp[k] * r) : (1.0f - (1.0f - mp[k]) * beta);
      const float xv   = (m0[k] > 0.0f) ? resc : mp[k];
      x[k] = xv; sx += xv;
    } else x[k] = 0.0f;
  }
  const float xbar = wave_sum_f(sx) / 368.0f;
  const float tolv = 1e-3f + 1e-5f * fabsf(xbar);

  // ---- Phase 2: try-parallel rejection sampling ----
  // row key: partitionable split -> block (0, b) of key (0, 42)
  uint32_t k0, k1;
  tf_block(0u, 42u, 0u, (uint32_t)b, k0, k1);
  // ladder init: wave w holds key_{w} (w chain steps)
  for (int i = 0; i < w; ++i) {
    uint32_t t0, t1; tf_block(k0, k1, 0u, 0u, t0, t1); k0 = t0; k1 = t1;
  }

  uint32_t res = 0;
  int winner = -1;
  for (int base = 0; base < 2000; base += NWAVE) {
    // advance ladder by NWAVE (independent of this iter's draws -> ILP)
    uint32_t n0 = k0, n1 = k1;
    for (int i = 0; i < NWAVE; ++i) {
      uint32_t t0, t1; tf_block(n0, n1, 0u, 0u, t0, t1); n0 = t0; n1 = t1;
    }
    // subkey for this wave's try = keys_out[1] of split(key)
    uint32_t s0, s1; tf_block(k0, k1, 0u, 1u, s0, s1);

    res = 0;
    int myones = 0;
    #pragma unroll
    for (int k = 0; k < KREG; ++k) {
      const int c = l + 64 * k;
      if (c < WCOLS) {
        uint32_t y0, y1;
        tf_block(s0, s1, 0u, (uint32_t)c, y0, y1);
        const uint32_t bits = y0 ^ y1;                       // partitionable fold
        const float prob = fmaxf(0.0f,
            __uint_as_float((bits >> 9) | 0x3f800000u) - 1.0f);
        if (x[k] > prob) { res |= (1u << k); ++myones; }
      }
    }
    const int tot = wave_sum_i(myones);
    const bool okw = fabsf((float)tot / 368.0f - xbar) <= tolv;
    if (l == 0) acc_ls[w] = okw ? 1 : 0;
    __syncthreads();
    int win = -1;
    #pragma unroll
    for (int i = 0; i < NWAVE; ++i) {
      if (win < 0 && acc_ls[i]) win = i;
    }
    __syncthreads();            // acc_ls reused next iteration
    if (win >= 0) { winner = win; break; }
    k0 = n0; k1 = n1;
  }
  if (winner < 0) winner = NWAVE - 1;   // 2000-try cap: keep last result (try 1999)

  if (w == winner) {
    #pragma unroll
    for (int k = 0; k < KREG; ++k) {
      const int c = l + 64 * k;
      if (c < WCOLS) {
        const float acq = ((res >> k) & 1u) ? 1.0f : 0.0f;
        new_mask[b * WCOLS + c] = mk[k] + acq;
        fpm[b * WCOLS + c]      = x[k];
      }
    }
  }
}

// Elementwise masked kspace. Sign-fix in ref == "+0 wherever mask==0".
__global__ __launch_bounds__(256) void apply_mask(const float4* __restrict__ ks,
                                                  const float* __restrict__ nm,
                                                  float4* __restrict__ out) {
  const int q = blockIdx.x * 256 + threadIdx.x;   // grid covers KS_F4 exactly
  const int b  = q / PER_B_F4;
  const int qw = q % ROW_F4;
  const int w0 = qw * 2;
  const float mA = nm[b * WCOLS + w0];
  const float mB = nm[b * WCOLS + w0 + 1];
  const float4 v = ks[q];
  float4 o;
  o.x = (mA != 0.0f) ? mA * v.x : 0.0f;
  o.y = (mA != 0.0f) ? mA * v.y : 0.0f;
  o.z = (mB != 0.0f) ? mB * v.z : 0.0f;
  o.w = (mB != 0.0f) ? mB * v.w : 0.0f;
  out[q] = o;
}

extern "C" void kernel_launch(void* const* d_in, const int* in_sizes, int n_in,
                              void* d_out, int out_size, void* d_ws, size_t ws_size,
                              hipStream_t stream) {
  const float* mask    = (const float*)d_in[0];
  const float* kspace  = (const float*)d_in[1];
  const float* sampler = (const float*)d_in[2];

  float* out      = (float*)d_out;
  float* new_mask = out;                              // B*W = 1472
  float* mkspace  = out + NROWS * WCOLS;              // 30146560
  float* fpm      = out + NROWS * WCOLS + KS_FLOATS;  // 1472

  sample_rows<<<NROWS, 1024, 0, stream>>>(mask, sampler, new_mask, fpm);
  apply_mask<<<KS_F4 / 256, 256, 0, stream>>>((const float4*)kspace, new_mask,
                                              (float4*)mkspace);
}

// Round 3
// 246.557 us; speedup vs baseline: 1.2548x; 1.0863x over previous
//
#include <hip/hip_runtime.h>
#include <stdint.h>

#define NROWS 4
#define WCOLS 368
#define KREG  6          // ceil(368/64)
#define NWAVE 16         // tries evaluated per super-iteration
#define KS_FLOATS 30146560   // 4*16*640*368*2
#define KS_F4     7536640    // /4
#define PER_B_F4  1884160    // 16*640*368*2/4
#define ROW_F4    184        // 368*2/4

// ---------------- Threefry-2x32, 20 rounds (JAX-compatible) ----------------
__device__ __forceinline__ void tf_block(uint32_t k0, uint32_t k1,
                                         uint32_t x0, uint32_t x1,
                                         uint32_t& o0, uint32_t& o1) {
  const uint32_t ks2 = k0 ^ k1 ^ 0x1BD11BDAu;
#define TFR(r) { x0 += x1; x1 = (x1 << (r)) | (x1 >> (32 - (r))); x1 ^= x0; }
  x0 += k0; x1 += k1;
  TFR(13) TFR(15) TFR(26) TFR(6)
  x0 += k1;  x1 += ks2 + 1u;
  TFR(17) TFR(29) TFR(16) TFR(24)
  x0 += ks2; x1 += k0 + 2u;
  TFR(13) TFR(15) TFR(26) TFR(6)
  x0 += k0;  x1 += k1 + 3u;
  TFR(17) TFR(29) TFR(16) TFR(24)
  x0 += k1;  x1 += ks2 + 4u;
  TFR(13) TFR(15) TFR(26) TFR(6)
  x0 += ks2; x1 += k0 + 5u;
#undef TFR
  o0 = x0; o1 = x1;
}

__device__ __forceinline__ float wave_sum_f(float v) {
  #pragma unroll
  for (int off = 32; off >= 1; off >>= 1) v += __shfl_xor(v, off, 64);
  return v;
}
__device__ __forceinline__ float wave_max_f(float v) {
  #pragma unroll
  for (int off = 32; off >= 1; off >>= 1) v = fmaxf(v, __shfl_xor(v, off, 64));
  return v;
}
__device__ __forceinline__ int wave_sum_i(int v) {
  #pragma unroll
  for (int off = 32; off >= 1; off >>= 1) v += __shfl_xor(v, off, 64);
  return v;
}

// One 1024-thread block per batch row. 16 waves evaluate 16 consecutive
// tries concurrently. The Threefry key chain (the only serial dependency)
// is extended 16 steps per super-iteration by a single rotating duty wave
// into a double-buffered LDS key table; all other waves just read their
// try's key from LDS. First-accept scan preserves sequential semantics.
__global__ __launch_bounds__(1024) void sample_rows(const float* __restrict__ mask,
                                                    const float* __restrict__ sampler,
                                                    float* __restrict__ new_mask,
                                                    float* __restrict__ fpm) {
  const int b = blockIdx.x;
  const int w = threadIdx.x >> 6;   // wave id 0..15 == try offset within group
  const int l = threadIdx.x & 63;

  __shared__ uint32_t keybuf[2][NWAVE][2];  // keybuf[buf][i] = chain key for try base+i
  __shared__ int acc_ls[NWAVE];

  // ---- Phase 1: probability pipeline (redundant per wave; identical fp ops
  // across waves -> identical x[], xbar in every wave) ----
  float mk[KREG], pmv[KREG], mp[KREG], m0[KREG], x[KREG];

  float vmax = 0.0f;
  #pragma unroll
  for (int k = 0; k < KREG; ++k) {
    const int c = l + 64 * k;
    if (c < WCOLS) {
      const float s  = sampler[c];
      const float mv = mask[b * WCOLS + c];
      const float z  = 10.0f * s;
      const float sp = (fmaxf(z, 0.0f) + log1pf(expf(-fabsf(z)))) / 10.0f;
      mk[k] = mv; pmv[k] = sp;
      vmax = fmaxf(vmax, (1.0f - mv) * sp);
    } else { mk[k] = 1.0f; pmv[k] = 0.0f; }
  }
  const float denom = wave_max_f(vmax);

  float cnt0 = 0.0f, smp = 0.0f;
  #pragma unroll
  for (int k = 0; k < KREG; ++k) {
    const int c = l + 64 * k;
    if (c < WCOLS) {
      const float pn  = pmv[k] / denom;
      const float mpv = pn * (1.0f - mk[k]);
      const float z0  = (mk[k] == 0.0f) ? 1.0f : 0.0f;
      mp[k] = mpv; m0[k] = z0;
      cnt0 += z0; smp += mpv * z0;
    } else { mp[k] = 0.0f; m0[k] = 0.0f; }
  }
  const float count    = wave_sum_f(cnt0);
  const float sumx     = wave_sum_f(smp);
  const float sparsity = 92.0f / count;
  const float xbar_pre = sumx / count;
  const float r    = sparsity / xbar_pre;
  const float beta = (1.0f - sparsity) / (1.0f - xbar_pre);
  const bool  le   = (r <= 1.0f);

  float sx = 0.0f;
  #pragma unroll
  for (int k = 0; k < KREG; ++k) {
    const int c = l + 64 * k;
    if (c < WCOLS) {
      const float resc = le ? (mp[k] * r) : (1.0f - (1.0f - mp[k]) * beta);
      const float xv   = (m0[k] > 0.0f) ? resc : mp[k];
      x[k] = xv; sx += xv;
    } else x[k] = 0.0f;
  }
  const float xbar = wave_sum_f(sx) / 368.0f;
  const float tolv = 1e-3f + 1e-5f * fabsf(xbar);

  // ---- Phase 2: try-parallel rejection sampling ----
  // row key: partitionable split -> block (0, b) of key (0, 42)
  uint32_t rk0, rk1;
  tf_block(0u, 42u, 0u, (uint32_t)b, rk0, rk1);

  // prologue: wave 0 fills keybuf[0][i] = key_i for tries 0..15
  if (w == 0) {
    uint32_t c0 = rk0, c1 = rk1;
    for (int i = 0; i < NWAVE; ++i) {
      if (l == 0) { keybuf[0][i][0] = c0; keybuf[0][i][1] = c1; }
      uint32_t t0, t1; tf_block(c0, c1, 0u, 0u, t0, t1); c0 = t0; c1 = t1;
    }
  }
  __syncthreads();

  uint32_t res = 0;
  int winner = -1;
  int cur = 0;
  for (int it = 0; it < 125; ++it) {           // 125*16 = 2000-try cap
    const uint32_t k0 = keybuf[cur][w][0];
    const uint32_t k1 = keybuf[cur][w][1];

    // rotating duty wave extends the chain 16 steps into the other buffer;
    // its dependent latency overlaps with its own independent draw work below
    if (w == (it & (NWAVE - 1))) {
      uint32_t c0 = keybuf[cur][NWAVE - 1][0];
      uint32_t c1 = keybuf[cur][NWAVE - 1][1];
      for (int i = 0; i < NWAVE; ++i) {
        uint32_t t0, t1; tf_block(c0, c1, 0u, 0u, t0, t1); c0 = t0; c1 = t1;
        if (l == 0) { keybuf[cur ^ 1][i][0] = c0; keybuf[cur ^ 1][i][1] = c1; }
      }
    }

    // subkey for this wave's try = keys_out[1] of split(key)
    uint32_t s0, s1; tf_block(k0, k1, 0u, 1u, s0, s1);

    res = 0;
    int myones = 0;
    #pragma unroll
    for (int k = 0; k < KREG; ++k) {
      const int c = l + 64 * k;
      if (c < WCOLS) {
        uint32_t y0, y1;
        tf_block(s0, s1, 0u, (uint32_t)c, y0, y1);
        const uint32_t bits = y0 ^ y1;                       // partitionable fold
        const float prob = fmaxf(0.0f,
            __uint_as_float((bits >> 9) | 0x3f800000u) - 1.0f);
        if (x[k] > prob) { res |= (1u << k); ++myones; }
      }
    }
    const int tot = wave_sum_i(myones);
    const bool okw = fabsf((float)tot / 368.0f - xbar) <= tolv;
    if (l == 0) acc_ls[w] = okw ? 1 : 0;
    __syncthreads();                 // flags + next-iter keybuf ready
    int win = -1;
    #pragma unroll
    for (int i = 0; i < NWAVE; ++i) {
      if (win < 0 && acc_ls[i]) win = i;
    }
    __syncthreads();                 // acc_ls / keybuf[cur] reusable
    if (win >= 0) { winner = win; break; }
    cur ^= 1;
  }
  if (winner < 0) winner = NWAVE - 1;   // 2000-try cap: keep last result (try 1999)

  if (w == winner) {
    #pragma unroll
    for (int k = 0; k < KREG; ++k) {
      const int c = l + 64 * k;
      if (c < WCOLS) {
        const float acq = ((res >> k) & 1u) ? 1.0f : 0.0f;
        new_mask[b * WCOLS + c] = mk[k] + acq;
        fpm[b * WCOLS + c]      = x[k];
      }
    }
  }
}

// Elementwise masked kspace. Sign-fix in ref == "+0 wherever mask==0".
__global__ __launch_bounds__(256) void apply_mask(const float4* __restrict__ ks,
                                                  const float* __restrict__ nm,
                                                  float4* __restrict__ out) {
  const int q = blockIdx.x * 256 + threadIdx.x;   // grid covers KS_F4 exactly
  const int b  = q / PER_B_F4;
  const int qw = q % ROW_F4;
  const int w0 = qw * 2;
  const float mA = nm[b * WCOLS + w0];
  const float mB = nm[b * WCOLS + w0 + 1];
  const float4 v = ks[q];
  float4 o;
  o.x = (mA != 0.0f) ? mA * v.x : 0.0f;
  o.y = (mA != 0.0f) ? mA * v.y : 0.0f;
  o.z = (mB != 0.0f) ? mB * v.z : 0.0f;
  o.w = (mB != 0.0f) ? mB * v.w : 0.0f;
  out[q] = o;
}

extern "C" void kernel_launch(void* const* d_in, const int* in_sizes, int n_in,
                              void* d_out, int out_size, void* d_ws, size_t ws_size,
                              hipStream_t stream) {
  const float* mask    = (const float*)d_in[0];
  const float* kspace  = (const float*)d_in[1];
  const float* sampler = (const float*)d_in[2];

  float* out      = (float*)d_out;
  float* new_mask = out;                              // B*W = 1472
  float* mkspace  = out + NROWS * WCOLS;              // 30146560
  float* fpm      = out + NROWS * WCOLS + KS_FLOATS;  // 1472

  sample_rows<<<NROWS, 1024, 0, stream>>>(mask, sampler, new_mask, fpm);
  apply_mask<<<KS_F4 / 256, 256, 0, stream>>>((const float4*)kspace, new_mask,
                                              (float4*)mkspace);
}